// Round 2
// baseline (153.143 us; speedup 1.0000x reference)
//
#include <hip/hip_runtime.h>

// Problem constants
#define NB 2048     // batch
#define NN 64       // nodes
#define KFIN 96
#define KFOUT 128
#define KOPD 48

typedef __attribute__((ext_vector_type(8))) short bf8;      // 8 bf16 (4 VGPRs) MFMA A/B frag
typedef __attribute__((ext_vector_type(4))) float f32x4;    // MFMA C/D frag
typedef __attribute__((ext_vector_type(4))) unsigned short us4;

__device__ __forceinline__ unsigned short f2bf(float f) {   // f32 -> bf16 RNE
  unsigned int u = __builtin_bit_cast(unsigned int, f);
  u += 0x7fffu + ((u >> 16) & 1u);
  return (unsigned short)(u >> 16);
}
__device__ __forceinline__ float bf2f(unsigned short s) {
  unsigned int u = ((unsigned int)s) << 16;
  return __builtin_bit_cast(float, u);
}
__device__ __forceinline__ us4 pack4(float a, float b, float c, float d) {
  us4 q; q.x = f2bf(a); q.y = f2bf(b); q.z = f2bf(c); q.w = f2bf(d); return q;
}
__device__ __forceinline__ bf8 pk8(float4 a, float4 b) {
  bf8 r;
  r[0] = (short)f2bf(a.x); r[1] = (short)f2bf(a.y); r[2] = (short)f2bf(a.z); r[3] = (short)f2bf(a.w);
  r[4] = (short)f2bf(b.x); r[5] = (short)f2bf(b.y); r[6] = (short)f2bf(b.z); r[7] = (short)f2bf(b.w);
  return r;
}
__device__ __forceinline__ unsigned int pk2(float lo, float hi) {
  return (unsigned int)f2bf(lo) | ((unsigned int)f2bf(hi) << 16);
}
__device__ __forceinline__ float unpk(unsigned int p, int hi) {
  return bf2f((unsigned short)(hi ? (p >> 16) : (p & 0xffffu)));
}

// ws layout (ushort): WT[128][96]@0, WkT[128][96]@12288,
// WopdT[128][64]@24576 (k 48..63 zero), WopgT[128][64]@32768. total 40960 elems.
__global__ void prep_weights(const float* __restrict__ W, const float* __restrict__ Wk,
                             const float* __restrict__ Wd, const float* __restrict__ Wg,
                             unsigned short* __restrict__ ws) {
  int idx = blockIdx.x * 256 + threadIdx.x;
  if (idx >= 40960) return;
  float v;
  if (idx < 12288)      { int o = idx / 96, f = idx % 96; v = W[f * 128 + o]; }
  else if (idx < 24576) { int r = idx - 12288; int o = r / 96, f = r % 96; v = Wk[f * 128 + o]; }
  else if (idx < 32768) { int r = idx - 24576; int o = r >> 6, k = r & 63; v = (k < 48) ? Wd[k * 128 + o] : 0.f; }
  else                  { int r = idx - 32768; int o = r >> 6, k = r & 63; v = (k < 48) ? Wg[k * 128 + o] : 0.f; }
  ws[idx] = f2bf(v);
}

// One block per batch element, 256 threads = 4 waves; wave w owns output rows [w*16, w*16+16).
// LDS (34304 B -> 4 blocks/CU):
//   buf1 [128][68] u16 @0      : supT (G1 out, G4 B)  ->  whkT (G6 B) after barrier2
//   buf2 [64][132] u16 @17408  : whk row-major (G5 A/B); attn [64][68] overlays after barrier4
// All MFMA A-operands (h, op_emb, adj) live in registers, loaded f32 from global.
#define LD1 68
#define LD2 132
#define LDA 68
__global__ __launch_bounds__(256, 4) void gin_fused(
    const float* __restrict__ hg, const float* __restrict__ adjg,
    const float* __restrict__ opeg, const float* __restrict__ bvec,
    const float* __restrict__ bopd, const float* __restrict__ bopg,
    const float* __restrict__ awv, const float* __restrict__ gmv,
    const float* __restrict__ btv, const unsigned short* __restrict__ ws,
    float* __restrict__ out) {
  __shared__ __align__(16) char smem[34304];
  unsigned short* buf1 = (unsigned short*)smem;             // supT -> whkT
  unsigned short* buf2 = (unsigned short*)(smem + 17408);   // whk -> attn

  const int t  = threadIdx.x;
  const int b  = blockIdx.x;
  const int w  = t >> 6;
  const int l  = t & 63;
  const int lr = l & 15;       // A-row / B-row / C-col lane index
  const int lg = l >> 4;       // k-group / C-row group
  const int kcol = 8 * lg;
  const int arow = w * 16 + lr;
  const int rowb = w * 16 + lg * 4;

  const float* hrow = hg   + (size_t)b * (NN * KFIN)  + arow * KFIN;
  const float* orow = opeg + (size_t)b * (NN * KOPD)  + arow * KOPD;
  const float* ajr  = adjg + (size_t)b * (NN * NN)    + arow * NN;

  // ---------------- register A-fragments (f32 global -> bf16) ----------------
  bf8 ha[3], oa[2], aa[2];
  #pragma unroll
  for (int kb = 0; kb < 3; ++kb) {
    float4 p0 = *(const float4*)(hrow + kb * 32 + kcol);
    float4 p1 = *(const float4*)(hrow + kb * 32 + kcol + 4);
    ha[kb] = pk8(p0, p1);
  }
  {
    float4 p0 = *(const float4*)(orow + kcol);
    float4 p1 = *(const float4*)(orow + kcol + 4);
    oa[0] = pk8(p0, p1);
    if (lg < 2) {
      float4 q0 = *(const float4*)(orow + 32 + kcol);
      float4 q1 = *(const float4*)(orow + 32 + kcol + 4);
      oa[1] = pk8(q0, q1);
    } else {
      bf8 z = {0, 0, 0, 0, 0, 0, 0, 0};
      oa[1] = z;
    }
  }
  #pragma unroll
  for (int kb = 0; kb < 2; ++kb) {
    float4 p0 = *(const float4*)(ajr + kb * 32 + kcol);
    float4 p1 = *(const float4*)(ajr + kb * 32 + kcol + 4);
    aa[kb] = pk8(p0, p1);
  }

  const unsigned short* WT  = ws;
  const unsigned short* WkT = ws + 12288;
  const unsigned short* WdT = ws + 24576;
  const unsigned short* WgT = ws + 32768;
  f32x4 zz = {0.f, 0.f, 0.f, 0.f};

  // ---------------- G1: support = h @ W (K=96) ----------------
  f32x4 sacc[8] = {zz, zz, zz, zz, zz, zz, zz, zz};
  #pragma unroll
  for (int kb = 0; kb < 3; ++kb) {
    #pragma unroll
    for (int nb = 0; nb < 8; ++nb) {
      bf8 bb = *(const bf8*)(WT + (nb * 16 + lr) * 96 + kb * 32 + kcol);
      sacc[nb] = __builtin_amdgcn_mfma_f32_16x16x32_bf16(ha[kb], bb, sacc[nb], 0, 0, 0);
    }
  }
  // support^T -> buf1 (B operand for G4)
  #pragma unroll
  for (int nb = 0; nb < 8; ++nb)
    *(us4*)(buf1 + (nb * 16 + lr) * LD1 + w * 16 + lg * 4) =
        pack4(sacc[nb][0], sacc[nb][1], sacc[nb][2], sacc[nb][3]);

  // ---------------- G3d: gate_d = sigmoid(ope @ Wop_d + bop_d) ----------------
  unsigned int gdp[8][2];
  {
    f32x4 gd[8] = {zz, zz, zz, zz, zz, zz, zz, zz};
    #pragma unroll
    for (int kb = 0; kb < 2; ++kb) {
      #pragma unroll
      for (int nb = 0; nb < 8; ++nb) {
        bf8 bb = *(const bf8*)(WdT + (nb * 16 + lr) * 64 + kb * 32 + kcol);
        gd[nb] = __builtin_amdgcn_mfma_f32_16x16x32_bf16(oa[kb], bb, gd[nb], 0, 0, 0);
      }
    }
    #pragma unroll
    for (int nb = 0; nb < 8; ++nb) {
      float bo = bopd[nb * 16 + lr];
      float g0 = 1.f / (1.f + __expf(-(gd[nb][0] + bo)));
      float g1 = 1.f / (1.f + __expf(-(gd[nb][1] + bo)));
      float g2 = 1.f / (1.f + __expf(-(gd[nb][2] + bo)));
      float g3 = 1.f / (1.f + __expf(-(gd[nb][3] + bo)));
      gdp[nb][0] = pk2(g0, g1); gdp[nb][1] = pk2(g2, g3);
    }
  }
  __syncthreads();   // b1: supT visible

  // ---------------- G4: dense = gate_d * (adj @ support) + support + b ----------------
  unsigned int dnp[8][2];
  #pragma unroll
  for (int nb = 0; nb < 8; ++nb) {
    f32x4 dacc = zz;
    #pragma unroll
    for (int kb = 0; kb < 2; ++kb) {
      bf8 bb = *(const bf8*)(buf1 + (nb * 16 + lr) * LD1 + kb * 32 + kcol);
      dacc = __builtin_amdgcn_mfma_f32_16x16x32_bf16(aa[kb], bb, dacc, 0, 0, 0);
    }
    float bc = bvec[nb * 16 + lr];
    float d0 = unpk(gdp[nb][0], 0) * dacc[0] + sacc[nb][0] + bc;
    float d1 = unpk(gdp[nb][0], 1) * dacc[1] + sacc[nb][1] + bc;
    float d2 = unpk(gdp[nb][1], 0) * dacc[2] + sacc[nb][2] + bc;
    float d3 = unpk(gdp[nb][1], 1) * dacc[3] + sacc[nb][3] + bc;
    dnp[nb][0] = pk2(d0, d1); dnp[nb][1] = pk2(d2, d3);
  }

  // ---------------- G2: Whk = h @ Wk (K=96) ----------------
  f32x4 wacc[8] = {zz, zz, zz, zz, zz, zz, zz, zz};
  #pragma unroll
  for (int kb = 0; kb < 3; ++kb) {
    #pragma unroll
    for (int nb = 0; nb < 8; ++nb) {
      bf8 bb = *(const bf8*)(WkT + (nb * 16 + lr) * 96 + kb * 32 + kcol);
      wacc[nb] = __builtin_amdgcn_mfma_f32_16x16x32_bf16(ha[kb], bb, wacc[nb], 0, 0, 0);
    }
  }
  __syncthreads();   // b2: all supT reads done; buf1/buf2 free for Whk

  // Whk^T -> buf1 ; Whk row-major -> buf2
  #pragma unroll
  for (int nb = 0; nb < 8; ++nb) {
    int o = nb * 16 + lr;
    *(us4*)(buf1 + o * LD1 + w * 16 + lg * 4) =
        pack4(wacc[nb][0], wacc[nb][1], wacc[nb][2], wacc[nb][3]);
    #pragma unroll
    for (int r = 0; r < 4; ++r)
      buf2[(w * 16 + lg * 4 + r) * LD2 + o] = f2bf(wacc[nb][r]);
  }

  // ---------------- G3g: gate_g ----------------
  unsigned int ggp[8][2];
  {
    f32x4 gg[8] = {zz, zz, zz, zz, zz, zz, zz, zz};
    #pragma unroll
    for (int kb = 0; kb < 2; ++kb) {
      #pragma unroll
      for (int nb = 0; nb < 8; ++nb) {
        bf8 bb = *(const bf8*)(WgT + (nb * 16 + lr) * 64 + kb * 32 + kcol);
        gg[nb] = __builtin_amdgcn_mfma_f32_16x16x32_bf16(oa[kb], bb, gg[nb], 0, 0, 0);
      }
    }
    #pragma unroll
    for (int nb = 0; nb < 8; ++nb) {
      float bo = bopg[nb * 16 + lr];
      float g0 = 1.f / (1.f + __expf(-(gg[nb][0] + bo)));
      float g1 = 1.f / (1.f + __expf(-(gg[nb][1] + bo)));
      float g2 = 1.f / (1.f + __expf(-(gg[nb][2] + bo)));
      float g3 = 1.f / (1.f + __expf(-(gg[nb][3] + bo)));
      ggp[nb][0] = pk2(g0, g1); ggp[nb][1] = pk2(g2, g3);
    }
  }

  // softmax adj-mask: prefetch before barrier so latency hides under G5
  float msk[4][4];
  #pragma unroll
  for (int jb = 0; jb < 4; ++jb)
    #pragma unroll
    for (int r = 0; r < 4; ++r)
      msk[jb][r] = adjg[(size_t)b * (NN * NN) + (rowb + r) * NN + jb * 16 + lr];

  __syncthreads();   // b3: whk + whkT visible

  // ---------------- G5: scores = (Whk * a_w) @ Whk^T (K=128) ----------------
  f32x4 sc[4] = {zz, zz, zz, zz};
  #pragma unroll
  for (int kb = 0; kb < 4; ++kb) {
    bf8 ar = *(const bf8*)(buf2 + arow * LD2 + kb * 32 + kcol);
    const float4* ap = (const float4*)(awv + kb * 32 + kcol);
    float4 a0 = ap[0], a1 = ap[1];
    bf8 a;
    a[0] = (short)f2bf(bf2f((unsigned short)ar[0]) * a0.x);
    a[1] = (short)f2bf(bf2f((unsigned short)ar[1]) * a0.y);
    a[2] = (short)f2bf(bf2f((unsigned short)ar[2]) * a0.z);
    a[3] = (short)f2bf(bf2f((unsigned short)ar[3]) * a0.w);
    a[4] = (short)f2bf(bf2f((unsigned short)ar[4]) * a1.x);
    a[5] = (short)f2bf(bf2f((unsigned short)ar[5]) * a1.y);
    a[6] = (short)f2bf(bf2f((unsigned short)ar[6]) * a1.z);
    a[7] = (short)f2bf(bf2f((unsigned short)ar[7]) * a1.w);
    #pragma unroll
    for (int jb = 0; jb < 4; ++jb) {
      bf8 bb = *(const bf8*)(buf2 + (jb * 16 + lr) * LD2 + kb * 32 + kcol);
      sc[jb] = __builtin_amdgcn_mfma_f32_16x16x32_bf16(a, bb, sc[jb], 0, 0, 0);
    }
  }

  // ---------------- softmax over j (leaky_relu then adj mask) ----------------
  float al[4][4];
  #pragma unroll
  for (int jb = 0; jb < 4; ++jb)
    #pragma unroll
    for (int r = 0; r < 4; ++r) {
      float s = sc[jb][r];
      al[jb][r] = (s >= 0.f ? s : 0.01f * s) * msk[jb][r];
    }
  #pragma unroll
  for (int r = 0; r < 4; ++r) {
    float m = fmaxf(fmaxf(al[0][r], al[1][r]), fmaxf(al[2][r], al[3][r]));
    m = fmaxf(m, __shfl_xor(m, 1));
    m = fmaxf(m, __shfl_xor(m, 2));
    m = fmaxf(m, __shfl_xor(m, 4));
    m = fmaxf(m, __shfl_xor(m, 8));
    float s0 = 0.f;
    #pragma unroll
    for (int jb = 0; jb < 4; ++jb) { float p = __expf(al[jb][r] - m); al[jb][r] = p; s0 += p; }
    s0 += __shfl_xor(s0, 1);
    s0 += __shfl_xor(s0, 2);
    s0 += __shfl_xor(s0, 4);
    s0 += __shfl_xor(s0, 8);
    float inv = 1.f / s0;
    #pragma unroll
    for (int jb = 0; jb < 4; ++jb) al[jb][r] *= inv;
  }
  __syncthreads();   // b4: all G5 reads of buf2 done -> attn may overwrite

  unsigned short* attn_s = buf2;   // [64][LDA]
  #pragma unroll
  for (int jb = 0; jb < 4; ++jb)
    #pragma unroll
    for (int r = 0; r < 4; ++r)
      attn_s[(rowb + r) * LDA + jb * 16 + lr] = f2bf(al[jb][r]);  // own rows only

  // ---------------- G6: hp = attn @ Whk (A: own attn rows; B: whkT in buf1) ----------------
  f32x4 hpacc[8] = {zz, zz, zz, zz, zz, zz, zz, zz};
  #pragma unroll
  for (int kb = 0; kb < 2; ++kb) {
    bf8 a = *(const bf8*)(attn_s + arow * LDA + kb * 32 + kcol);
    #pragma unroll
    for (int nb = 0; nb < 8; ++nb) {
      bf8 bb = *(const bf8*)(buf1 + (nb * 16 + lr) * LD1 + kb * 32 + kcol);
      hpacc[nb] = __builtin_amdgcn_mfma_f32_16x16x32_bf16(a, bb, hpacc[nb], 0, 0, 0);
    }
  }

  // ---------------- gate_g * hp, LayerNorm, combine, store ----------------
  float gam[8], bet[8];
  #pragma unroll
  for (int nb = 0; nb < 8; ++nb) { gam[nb] = gmv[nb * 16 + lr]; bet[nb] = btv[nb * 16 + lr]; }
  float* outp = out + (size_t)b * (NN * KFOUT);
  #pragma unroll
  for (int r = 0; r < 4; ++r) {
    float hv[8]; float su = 0.f, sq = 0.f;
    #pragma unroll
    for (int nb = 0; nb < 8; ++nb) {
      float v = unpk(ggp[nb][r >> 1], r & 1) * hpacc[nb][r];
      hv[nb] = v; su += v; sq += v * v;
    }
    su += __shfl_xor(su, 1); su += __shfl_xor(su, 2);
    su += __shfl_xor(su, 4); su += __shfl_xor(su, 8);
    sq += __shfl_xor(sq, 1); sq += __shfl_xor(sq, 2);
    sq += __shfl_xor(sq, 4); sq += __shfl_xor(sq, 8);
    float mean = su * (1.f / 128.f);
    float var  = sq * (1.f / 128.f) - mean * mean;
    float rinv = rsqrtf(var + 1e-5f);
    int row = rowb + r;
    #pragma unroll
    for (int nb = 0; nb < 8; ++nb) {
      float hn = (hv[nb] - mean) * rinv * gam[nb] + bet[nb];
      float dv = unpk(dnp[nb][r >> 1], r & 1);
      outp[row * 128 + nb * 16 + lr] = (dv + hn) * 0.5f;
    }
  }
}

extern "C" void kernel_launch(void* const* d_in, const int* in_sizes, int n_in,
                              void* d_out, int out_size, void* d_ws, size_t ws_size,
                              hipStream_t stream) {
  const float* h     = (const float*)d_in[0];
  const float* adj   = (const float*)d_in[1];
  const float* ope   = (const float*)d_in[2];
  const float* W     = (const float*)d_in[3];
  const float* bvec  = (const float*)d_in[4];
  const float* Wopd  = (const float*)d_in[5];
  const float* bopd  = (const float*)d_in[6];
  const float* Wk    = (const float*)d_in[7];
  const float* a_w   = (const float*)d_in[8];
  const float* Wopg  = (const float*)d_in[9];
  const float* bopg  = (const float*)d_in[10];
  const float* gamma = (const float*)d_in[11];
  const float* beta  = (const float*)d_in[12];
  float* out = (float*)d_out;
  unsigned short* ws = (unsigned short*)d_ws;

  prep_weights<<<dim3(160), dim3(256), 0, stream>>>(W, Wk, Wopd, Wopg, ws);
  gin_fused<<<dim3(NB), dim3(256), 0, stream>>>(h, adj, ope, bvec, bopd, bopg,
                                                a_w, gamma, beta, ws, out);
}

// Round 3
// 140.606 us; speedup vs baseline: 1.0892x; 1.0892x over previous
//
#include <hip/hip_runtime.h>

// Problem constants
#define NB 2048     // batch
#define NN 64       // nodes
#define KFIN 96
#define KFOUT 128
#define KOPD 48

typedef __attribute__((ext_vector_type(8))) short bf8;      // 8 bf16 MFMA A/B frag
typedef __attribute__((ext_vector_type(4))) float f32x4;    // MFMA C/D frag
typedef __attribute__((ext_vector_type(4))) unsigned short us4;
typedef __attribute__((ext_vector_type(2))) __bf16 bfx2;

__device__ __forceinline__ unsigned short f2bf(float f) {   // f32 -> bf16 RNE (HW cvt)
  __bf16 h = (__bf16)f;
  return __builtin_bit_cast(unsigned short, h);
}
__device__ __forceinline__ float bf2f(unsigned short s) {
  unsigned int u = ((unsigned int)s) << 16;
  return __builtin_bit_cast(float, u);
}
__device__ __forceinline__ us4 pack4(float a, float b, float c, float d) {
  us4 q; q.x = f2bf(a); q.y = f2bf(b); q.z = f2bf(c); q.w = f2bf(d); return q;
}
__device__ __forceinline__ bf8 pk8(float4 a, float4 b) {
  bf8 r;
  r[0] = (short)f2bf(a.x); r[1] = (short)f2bf(a.y); r[2] = (short)f2bf(a.z); r[3] = (short)f2bf(a.w);
  r[4] = (short)f2bf(b.x); r[5] = (short)f2bf(b.y); r[6] = (short)f2bf(b.z); r[7] = (short)f2bf(b.w);
  return r;
}
__device__ __forceinline__ unsigned int pk2(float lo, float hi) {
  bfx2 v; v[0] = (__bf16)lo; v[1] = (__bf16)hi;
  return __builtin_bit_cast(unsigned int, v);
}
__device__ __forceinline__ float unpk(unsigned int p, int hi) {
  return bf2f((unsigned short)(hi ? (p >> 16) : (p & 0xffffu)));
}

// ws layout (ushort): WT[128][96]@0, WkT[128][96]@12288,
// WopdT[128][64]@24576 (k 48..63 zero), WopgT[128][64]@32768. total 40960 elems.
__global__ void prep_weights(const float* __restrict__ W, const float* __restrict__ Wk,
                             const float* __restrict__ Wd, const float* __restrict__ Wg,
                             unsigned short* __restrict__ ws) {
  int idx = blockIdx.x * 256 + threadIdx.x;
  if (idx >= 40960) return;
  float v;
  if (idx < 12288)      { int o = idx / 96, f = idx % 96; v = W[f * 128 + o]; }
  else if (idx < 24576) { int r = idx - 12288; int o = r / 96, f = r % 96; v = Wk[f * 128 + o]; }
  else if (idx < 32768) { int r = idx - 24576; int o = r >> 6, k = r & 63; v = (k < 48) ? Wd[k * 128 + o] : 0.f; }
  else                  { int r = idx - 32768; int o = r >> 6, k = r & 63; v = (k < 48) ? Wg[k * 128 + o] : 0.f; }
  ws[idx] = f2bf(v);
}

// One block per batch element, 256 threads = 4 waves; wave w owns output rows [w*16, w*16+16).
// Phase-split: dense branch completes and writes dense*0.5 to d_out (per-thread-private
// addresses, read back by the same thread at the end) BEFORE the attention branch starts,
// so at most one 32-reg accumulator array is live at any point.
// LDS (34304 B -> 4 blocks/CU, strides 68/132 measured conflict-free in R2):
//   buf1 [128][68] u16 @0      : supT (G1 out, G4 B)  ->  whkT (G6 B) after barrier2
//   buf2 [64][132] u16 @17408  : whk row-major (G5 A/B); attn [64][68] overlays after barrier4
#define LD1 68
#define LD2 132
#define LDA 68
__global__ __launch_bounds__(256, 4) void gin_fused(
    const float* __restrict__ hg, const float* __restrict__ adjg,
    const float* __restrict__ opeg, const float* __restrict__ bvec,
    const float* __restrict__ bopd, const float* __restrict__ bopg,
    const float* __restrict__ awv, const float* __restrict__ gmv,
    const float* __restrict__ btv, const unsigned short* __restrict__ ws,
    float* __restrict__ out) {
  __shared__ __align__(16) char smem[34304];
  unsigned short* buf1 = (unsigned short*)smem;             // supT -> whkT
  unsigned short* buf2 = (unsigned short*)(smem + 17408);   // whk -> attn

  const int t  = threadIdx.x;
  const int b  = blockIdx.x;
  const int w  = t >> 6;
  const int l  = t & 63;
  const int lr = l & 15;       // A-row / B-row / C-col lane index
  const int lg = l >> 4;       // k-group / C-row group
  const int kcol = 8 * lg;
  const int arow = w * 16 + lr;
  const int rowb = w * 16 + lg * 4;

  const float* hrow = hg   + (size_t)b * (NN * KFIN) + arow * KFIN;
  const float* orow = opeg + (size_t)b * (NN * KOPD) + arow * KOPD;
  float* outp = out + (size_t)b * (NN * KFOUT);

  const unsigned short* WT  = ws;
  const unsigned short* WkT = ws + 12288;
  const unsigned short* WdT = ws + 24576;
  const unsigned short* WgT = ws + 32768;
  f32x4 zz = {0.f, 0.f, 0.f, 0.f};

  // ---------------- A-fragments: op_emb (K pad 48->64) and h ----------------
  bf8 oa[2], ha[3];
  {
    float4 p0 = *(const float4*)(orow + kcol);
    float4 p1 = *(const float4*)(orow + kcol + 4);
    oa[0] = pk8(p0, p1);
    if (lg < 2) {
      float4 q0 = *(const float4*)(orow + 32 + kcol);
      float4 q1 = *(const float4*)(orow + 32 + kcol + 4);
      oa[1] = pk8(q0, q1);
    } else {
      bf8 z = {0, 0, 0, 0, 0, 0, 0, 0};
      oa[1] = z;
    }
  }
  #pragma unroll
  for (int kb = 0; kb < 3; ++kb) {
    float4 p0 = *(const float4*)(hrow + kb * 32 + kcol);
    float4 p1 = *(const float4*)(hrow + kb * 32 + kcol + 4);
    ha[kb] = pk8(p0, p1);
  }

  // ---------------- G3d: gate_d = sigmoid(ope @ Wop_d + bop_d) (before G1: no acc overlap) ----
  unsigned int gdp[8][2];
  {
    f32x4 gd[8] = {zz, zz, zz, zz, zz, zz, zz, zz};
    #pragma unroll
    for (int kb = 0; kb < 2; ++kb) {
      #pragma unroll
      for (int nb = 0; nb < 8; ++nb) {
        bf8 bb = *(const bf8*)(WdT + (nb * 16 + lr) * 64 + kb * 32 + kcol);
        gd[nb] = __builtin_amdgcn_mfma_f32_16x16x32_bf16(oa[kb], bb, gd[nb], 0, 0, 0);
      }
    }
    #pragma unroll
    for (int nb = 0; nb < 8; ++nb) {
      float bo = bopd[nb * 16 + lr];
      float g0 = 1.f / (1.f + __expf(-(gd[nb][0] + bo)));
      float g1 = 1.f / (1.f + __expf(-(gd[nb][1] + bo)));
      float g2 = 1.f / (1.f + __expf(-(gd[nb][2] + bo)));
      float g3 = 1.f / (1.f + __expf(-(gd[nb][3] + bo)));
      gdp[nb][0] = pk2(g0, g1); gdp[nb][1] = pk2(g2, g3);
    }
  }

  // ---------------- G1: support = h @ W (K=96) ----------------
  f32x4 sacc[8] = {zz, zz, zz, zz, zz, zz, zz, zz};
  #pragma unroll
  for (int kb = 0; kb < 3; ++kb) {
    #pragma unroll
    for (int nb = 0; nb < 8; ++nb) {
      bf8 bb = *(const bf8*)(WT + (nb * 16 + lr) * 96 + kb * 32 + kcol);
      sacc[nb] = __builtin_amdgcn_mfma_f32_16x16x32_bf16(ha[kb], bb, sacc[nb], 0, 0, 0);
    }
  }
  // support^T -> buf1 (B operand for G4)
  #pragma unroll
  for (int nb = 0; nb < 8; ++nb)
    *(us4*)(buf1 + (nb * 16 + lr) * LD1 + w * 16 + lg * 4) =
        pack4(sacc[nb][0], sacc[nb][1], sacc[nb][2], sacc[nb][3]);
  __syncthreads();   // b1: supT visible

  // ---------------- G4: dense = gate_d*(adj @ support) + support + b ; out = dense/2 ----------
  {
    const float* ajr = adjg + (size_t)b * (NN * NN) + arow * NN;
    bf8 aa[2];
    #pragma unroll
    for (int kb = 0; kb < 2; ++kb) {
      float4 p0 = *(const float4*)(ajr + kb * 32 + kcol);
      float4 p1 = *(const float4*)(ajr + kb * 32 + kcol + 4);
      aa[kb] = pk8(p0, p1);
    }
    #pragma unroll
    for (int nb = 0; nb < 8; ++nb) {
      f32x4 dacc = zz;
      #pragma unroll
      for (int kb = 0; kb < 2; ++kb) {
        bf8 bb = *(const bf8*)(buf1 + (nb * 16 + lr) * LD1 + kb * 32 + kcol);
        dacc = __builtin_amdgcn_mfma_f32_16x16x32_bf16(aa[kb], bb, dacc, 0, 0, 0);
      }
      float bc = bvec[nb * 16 + lr];
      int col = nb * 16 + lr;
      #pragma unroll
      for (int r = 0; r < 4; ++r) {
        float g = unpk(gdp[nb][r >> 1], r & 1);
        float d = g * dacc[r] + sacc[nb][r] + bc;
        outp[(rowb + r) * 128 + col] = 0.5f * d;    // partial: dense/2 (read back at end)
      }
    }
  }
  // sacc, gdp, aa dead here.

  // ---------------- G2: Whk = h @ Wk (K=96) ----------------
  f32x4 wacc[8] = {zz, zz, zz, zz, zz, zz, zz, zz};
  #pragma unroll
  for (int kb = 0; kb < 3; ++kb) {
    #pragma unroll
    for (int nb = 0; nb < 8; ++nb) {
      bf8 bb = *(const bf8*)(WkT + (nb * 16 + lr) * 96 + kb * 32 + kcol);
      wacc[nb] = __builtin_amdgcn_mfma_f32_16x16x32_bf16(ha[kb], bb, wacc[nb], 0, 0, 0);
    }
  }
  __syncthreads();   // b2: all supT reads (G4) done; buf1/buf2 free

  // Whk^T -> buf1 ; Whk row-major -> buf2 (wacc dies)
  #pragma unroll
  for (int nb = 0; nb < 8; ++nb) {
    int o = nb * 16 + lr;
    *(us4*)(buf1 + o * LD1 + w * 16 + lg * 4) =
        pack4(wacc[nb][0], wacc[nb][1], wacc[nb][2], wacc[nb][3]);
    #pragma unroll
    for (int r = 0; r < 4; ++r)
      buf2[(w * 16 + lg * 4 + r) * LD2 + o] = f2bf(wacc[nb][r]);
  }

  // ---------------- G3g: gate_g (oa dies after) ----------------
  unsigned int ggp[8][2];
  {
    f32x4 gg[8] = {zz, zz, zz, zz, zz, zz, zz, zz};
    #pragma unroll
    for (int kb = 0; kb < 2; ++kb) {
      #pragma unroll
      for (int nb = 0; nb < 8; ++nb) {
        bf8 bb = *(const bf8*)(WgT + (nb * 16 + lr) * 64 + kb * 32 + kcol);
        gg[nb] = __builtin_amdgcn_mfma_f32_16x16x32_bf16(oa[kb], bb, gg[nb], 0, 0, 0);
      }
    }
    #pragma unroll
    for (int nb = 0; nb < 8; ++nb) {
      float bo = bopg[nb * 16 + lr];
      float g0 = 1.f / (1.f + __expf(-(gg[nb][0] + bo)));
      float g1 = 1.f / (1.f + __expf(-(gg[nb][1] + bo)));
      float g2 = 1.f / (1.f + __expf(-(gg[nb][2] + bo)));
      float g3 = 1.f / (1.f + __expf(-(gg[nb][3] + bo)));
      ggp[nb][0] = pk2(g0, g1); ggp[nb][1] = pk2(g2, g3);
    }
  }
  __syncthreads();   // b3: whk + whkT visible

  // ---------------- G5: scores = (Whk * a_w) @ Whk^T (K=128) ----------------
  f32x4 sc[4] = {zz, zz, zz, zz};
  #pragma unroll
  for (int kb = 0; kb < 4; ++kb) {
    bf8 ar = *(const bf8*)(buf2 + arow * LD2 + kb * 32 + kcol);
    const float4* ap = (const float4*)(awv + kb * 32 + kcol);
    float4 a0 = ap[0], a1 = ap[1];
    bf8 a;
    a[0] = (short)f2bf(bf2f((unsigned short)ar[0]) * a0.x);
    a[1] = (short)f2bf(bf2f((unsigned short)ar[1]) * a0.y);
    a[2] = (short)f2bf(bf2f((unsigned short)ar[2]) * a0.z);
    a[3] = (short)f2bf(bf2f((unsigned short)ar[3]) * a0.w);
    a[4] = (short)f2bf(bf2f((unsigned short)ar[4]) * a1.x);
    a[5] = (short)f2bf(bf2f((unsigned short)ar[5]) * a1.y);
    a[6] = (short)f2bf(bf2f((unsigned short)ar[6]) * a1.z);
    a[7] = (short)f2bf(bf2f((unsigned short)ar[7]) * a1.w);
    #pragma unroll
    for (int jb = 0; jb < 4; ++jb) {
      bf8 bb = *(const bf8*)(buf2 + (jb * 16 + lr) * LD2 + kb * 32 + kcol);
      sc[jb] = __builtin_amdgcn_mfma_f32_16x16x32_bf16(a, bb, sc[jb], 0, 0, 0);
    }
  }

  // ---------------- softmax over j (leaky_relu then adj mask; mask loaded at use) ----------
  float al[4][4];
  #pragma unroll
  for (int jb = 0; jb < 4; ++jb)
    #pragma unroll
    for (int r = 0; r < 4; ++r) {
      float am = adjg[(size_t)b * (NN * NN) + (rowb + r) * NN + jb * 16 + lr];
      float s = sc[jb][r];
      al[jb][r] = (s >= 0.f ? s : 0.01f * s) * am;
    }
  #pragma unroll
  for (int r = 0; r < 4; ++r) {
    float m = fmaxf(fmaxf(al[0][r], al[1][r]), fmaxf(al[2][r], al[3][r]));
    m = fmaxf(m, __shfl_xor(m, 1));
    m = fmaxf(m, __shfl_xor(m, 2));
    m = fmaxf(m, __shfl_xor(m, 4));
    m = fmaxf(m, __shfl_xor(m, 8));
    float s0 = 0.f;
    #pragma unroll
    for (int jb = 0; jb < 4; ++jb) { float p = __expf(al[jb][r] - m); al[jb][r] = p; s0 += p; }
    s0 += __shfl_xor(s0, 1);
    s0 += __shfl_xor(s0, 2);
    s0 += __shfl_xor(s0, 4);
    s0 += __shfl_xor(s0, 8);
    float inv = 1.f / s0;
    #pragma unroll
    for (int jb = 0; jb < 4; ++jb) al[jb][r] *= inv;
  }
  __syncthreads();   // b4: all G5 reads of buf2 done -> attn may overwrite

  unsigned short* attn_s = buf2;   // [64][LDA] overlay
  #pragma unroll
  for (int jb = 0; jb < 4; ++jb)
    #pragma unroll
    for (int r = 0; r < 4; ++r)
      attn_s[(rowb + r) * LDA + jb * 16 + lr] = f2bf(al[jb][r]);  // own wave's rows only

  // ---------------- G6: hp = attn @ Whk (A: own attn rows; B: whkT in buf1) ----------------
  f32x4 hpacc[8] = {zz, zz, zz, zz, zz, zz, zz, zz};
  #pragma unroll
  for (int kb = 0; kb < 2; ++kb) {
    bf8 a = *(const bf8*)(attn_s + arow * LDA + kb * 32 + kcol);
    #pragma unroll
    for (int nb = 0; nb < 8; ++nb) {
      bf8 bb = *(const bf8*)(buf1 + (nb * 16 + lr) * LD1 + kb * 32 + kcol);
      hpacc[nb] = __builtin_amdgcn_mfma_f32_16x16x32_bf16(a, bb, hpacc[nb], 0, 0, 0);
    }
  }

  // ---------------- gate_g * hp, LayerNorm, combine with dense/2 from out, store ----------
  float gam[8], bet[8];
  #pragma unroll
  for (int nb = 0; nb < 8; ++nb) { gam[nb] = gmv[nb * 16 + lr]; bet[nb] = btv[nb * 16 + lr]; }
  #pragma unroll
  for (int r = 0; r < 4; ++r) {
    float hv[8]; float su = 0.f, sq = 0.f;
    #pragma unroll
    for (int nb = 0; nb < 8; ++nb) {
      float v = unpk(ggp[nb][r >> 1], r & 1) * hpacc[nb][r];
      hv[nb] = v; su += v; sq += v * v;
    }
    su += __shfl_xor(su, 1); su += __shfl_xor(su, 2);
    su += __shfl_xor(su, 4); su += __shfl_xor(su, 8);
    sq += __shfl_xor(sq, 1); sq += __shfl_xor(sq, 2);
    sq += __shfl_xor(sq, 4); sq += __shfl_xor(sq, 8);
    float mean = su * (1.f / 128.f);
    float var  = sq * (1.f / 128.f) - mean * mean;
    float rinv = rsqrtf(var + 1e-5f);
    int row = rowb + r;
    #pragma unroll
    for (int nb = 0; nb < 8; ++nb) {
      float hn = (hv[nb] - mean) * rinv * gam[nb] + bet[nb];
      float dv = outp[row * 128 + nb * 16 + lr];    // dense/2 written by this same thread
      outp[row * 128 + nb * 16 + lr] = dv + 0.5f * hn;
    }
  }
}

extern "C" void kernel_launch(void* const* d_in, const int* in_sizes, int n_in,
                              void* d_out, int out_size, void* d_ws, size_t ws_size,
                              hipStream_t stream) {
  const float* h     = (const float*)d_in[0];
  const float* adj   = (const float*)d_in[1];
  const float* ope   = (const float*)d_in[2];
  const float* W     = (const float*)d_in[3];
  const float* bvec  = (const float*)d_in[4];
  const float* Wopd  = (const float*)d_in[5];
  const float* bopd  = (const float*)d_in[6];
  const float* Wk    = (const float*)d_in[7];
  const float* a_w   = (const float*)d_in[8];
  const float* Wopg  = (const float*)d_in[9];
  const float* bopg  = (const float*)d_in[10];
  const float* gamma = (const float*)d_in[11];
  const float* beta  = (const float*)d_in[12];
  float* out = (float*)d_out;
  unsigned short* ws = (unsigned short*)d_ws;

  prep_weights<<<dim3(160), dim3(256), 0, stream>>>(W, Wk, Wopd, Wopg, ws);
  gin_fused<<<dim3(NB), dim3(256), 0, stream>>>(h, adj, ope, bvec, bopd, bopg,
                                                a_w, gamma, beta, ws, out);
}

// Round 4
// 103.213 us; speedup vs baseline: 1.4838x; 1.3623x over previous
//
#include <hip/hip_runtime.h>

// Problem constants
#define NB 2048     // batch
#define NN 64       // nodes
#define KFIN 96
#define KFOUT 128
#define KOPD 48

typedef __attribute__((ext_vector_type(8))) short bf8;      // 8 bf16 MFMA A/B frag
typedef __attribute__((ext_vector_type(4))) float f32x4;    // MFMA C/D frag
typedef __attribute__((ext_vector_type(4))) unsigned short us4;
typedef __attribute__((ext_vector_type(2))) __bf16 bfx2;

__device__ __forceinline__ unsigned short f2bf(float f) {   // f32 -> bf16 RNE (HW cvt)
  __bf16 h = (__bf16)f;
  return __builtin_bit_cast(unsigned short, h);
}
__device__ __forceinline__ float bf2f(unsigned short s) {
  unsigned int u = ((unsigned int)s) << 16;
  return __builtin_bit_cast(float, u);
}
__device__ __forceinline__ us4 pack4(float a, float b, float c, float d) {
  us4 q; q.x = f2bf(a); q.y = f2bf(b); q.z = f2bf(c); q.w = f2bf(d); return q;
}
__device__ __forceinline__ bf8 pk8(float4 a, float4 b) {
  bf8 r;
  r[0] = (short)f2bf(a.x); r[1] = (short)f2bf(a.y); r[2] = (short)f2bf(a.z); r[3] = (short)f2bf(a.w);
  r[4] = (short)f2bf(b.x); r[5] = (short)f2bf(b.y); r[6] = (short)f2bf(b.z); r[7] = (short)f2bf(b.w);
  return r;
}
__device__ __forceinline__ unsigned int pk2(float lo, float hi) {
  bfx2 v; v[0] = (__bf16)lo; v[1] = (__bf16)hi;
  return __builtin_bit_cast(unsigned int, v);
}
__device__ __forceinline__ float unpk(unsigned int p, int hi) {
  return bf2f((unsigned short)(hi ? (p >> 16) : (p & 0xffffu)));
}

// ws layout (ushort), FRAGMENT-ORDERED so weight loads are lane-coalesced:
//   for each matrix: frag[(nb*NKB + kb)*512 + l*8 + e] = Mat[k][o]
//   with o = nb*16 + (l&15), k = kb*32 + (l>>4)*8 + e.
//   WT  @ 0      (NKB=3, 12288 elems)   from W  [96][128]
//   WkT @ 12288  (NKB=3, 12288)         from Wk [96][128]
//   WdT @ 24576  (NKB=2, 8192, k>=48→0) from Wd [48][128]
//   WgT @ 32768  (NKB=2, 8192, k>=48→0) from Wg [48][128]
__global__ void prep_weights(const float* __restrict__ W, const float* __restrict__ Wk,
                             const float* __restrict__ Wd, const float* __restrict__ Wg,
                             unsigned short* __restrict__ ws) {
  int idx = blockIdx.x * 256 + threadIdx.x;
  if (idx >= 40960) return;
  float v;
  if (idx < 24576) {          // W or Wk, NKB=3
    int r  = (idx < 12288) ? idx : idx - 12288;
    const float* M = (idx < 12288) ? W : Wk;
    int nb = r / 1536, rem = r % 1536;
    int kb = rem / 512, rem2 = rem % 512;
    int l = rem2 >> 3, e = rem2 & 7;
    int o = nb * 16 + (l & 15);
    int k = kb * 32 + (l >> 4) * 8 + e;
    v = M[k * 128 + o];
  } else {                    // Wd or Wg, NKB=2, K padded 48->64
    int r  = (idx < 32768) ? idx - 24576 : idx - 32768;
    const float* M = (idx < 32768) ? Wd : Wg;
    int nb = r / 1024, rem = r % 1024;
    int kb = rem / 512, rem2 = rem % 512;
    int l = rem2 >> 3, e = rem2 & 7;
    int o = nb * 16 + (l & 15);
    int k = kb * 32 + (l >> 4) * 8 + e;
    v = (k < 48) ? M[k * 128 + o] : 0.f;
  }
  ws[idx] = f2bf(v);
}

// One block per batch element, 256 threads = 4 waves; wave w owns output rows [w*16, w*16+16).
// Dense result held in 16 packed-bf16 u32 regs (dnp) across the attention phase.
// LDS (34304 B -> 4 blocks/CU, strides conflict-checked in R2):
//   buf1 [128][68] u16 @0      : supT (G1 out, G4 B)  ->  whkT (G6 B) after barrier2
//   buf2 [64][132] u16 @17408  : whk row-major (G5 A/B); attn [64][68] overlays after barrier4
#define LD1 68
#define LD2 132
#define LDA 68
__global__ __launch_bounds__(256, 4) void gin_fused(
    const float* __restrict__ hg, const float* __restrict__ adjg,
    const float* __restrict__ opeg, const float* __restrict__ bvec,
    const float* __restrict__ bopd, const float* __restrict__ bopg,
    const float* __restrict__ awv, const float* __restrict__ gmv,
    const float* __restrict__ btv, const unsigned short* __restrict__ ws,
    float* __restrict__ out) {
  __shared__ __align__(16) char smem[34304];
  unsigned short* buf1 = (unsigned short*)smem;             // supT -> whkT
  unsigned short* buf2 = (unsigned short*)(smem + 17408);   // whk -> attn

  const int t  = threadIdx.x;
  const int b  = blockIdx.x;
  const int w  = t >> 6;
  const int l  = t & 63;
  const int lr = l & 15;       // A-row / B-row / C-col lane index
  const int lg = l >> 4;       // k-group / C-row group
  const int kcol = 8 * lg;
  const int arow = w * 16 + lr;
  const int rowb = w * 16 + lg * 4;

  const float* hrow = hg   + (size_t)b * (NN * KFIN) + arow * KFIN;
  const float* orow = opeg + (size_t)b * (NN * KOPD) + arow * KOPD;
  float* outp = out + (size_t)b * (NN * KFOUT);

  const unsigned short* WT  = ws;
  const unsigned short* WkT = ws + 12288;
  const unsigned short* WdT = ws + 24576;
  const unsigned short* WgT = ws + 32768;
  f32x4 zz = {0.f, 0.f, 0.f, 0.f};

  // ---------------- A-fragments: op_emb (K pad 48->64) and h ----------------
  bf8 oa[2], ha[3];
  {
    float4 p0 = *(const float4*)(orow + kcol);
    float4 p1 = *(const float4*)(orow + kcol + 4);
    oa[0] = pk8(p0, p1);
    if (lg < 2) {
      float4 q0 = *(const float4*)(orow + 32 + kcol);
      float4 q1 = *(const float4*)(orow + 32 + kcol + 4);
      oa[1] = pk8(q0, q1);
    } else {
      bf8 z = {0, 0, 0, 0, 0, 0, 0, 0};
      oa[1] = z;
    }
  }
  #pragma unroll
  for (int kb = 0; kb < 3; ++kb) {
    float4 p0 = *(const float4*)(hrow + kb * 32 + kcol);
    float4 p1 = *(const float4*)(hrow + kb * 32 + kcol + 4);
    ha[kb] = pk8(p0, p1);
  }

  // ---------------- G3d: gate_d = sigmoid(ope @ Wop_d + bop_d) ----------------
  unsigned int gdp[8][2];
  {
    f32x4 gd[8] = {zz, zz, zz, zz, zz, zz, zz, zz};
    #pragma unroll
    for (int kb = 0; kb < 2; ++kb) {
      #pragma unroll
      for (int nb = 0; nb < 8; ++nb) {
        bf8 bb = *(const bf8*)(WdT + (nb * 2 + kb) * 512 + l * 8);   // coalesced frag
        gd[nb] = __builtin_amdgcn_mfma_f32_16x16x32_bf16(oa[kb], bb, gd[nb], 0, 0, 0);
      }
    }
    #pragma unroll
    for (int nb = 0; nb < 8; ++nb) {
      float bo = bopd[nb * 16 + lr];
      float g0 = 1.f / (1.f + __expf(-(gd[nb][0] + bo)));
      float g1 = 1.f / (1.f + __expf(-(gd[nb][1] + bo)));
      float g2 = 1.f / (1.f + __expf(-(gd[nb][2] + bo)));
      float g3 = 1.f / (1.f + __expf(-(gd[nb][3] + bo)));
      gdp[nb][0] = pk2(g0, g1); gdp[nb][1] = pk2(g2, g3);
    }
  }

  // ---------------- G1: support = h @ W (K=96) ----------------
  f32x4 sacc[8] = {zz, zz, zz, zz, zz, zz, zz, zz};
  #pragma unroll
  for (int kb = 0; kb < 3; ++kb) {
    #pragma unroll
    for (int nb = 0; nb < 8; ++nb) {
      bf8 bb = *(const bf8*)(WT + (nb * 3 + kb) * 512 + l * 8);      // coalesced frag
      sacc[nb] = __builtin_amdgcn_mfma_f32_16x16x32_bf16(ha[kb], bb, sacc[nb], 0, 0, 0);
    }
  }
  // support^T -> buf1 (B operand for G4)
  #pragma unroll
  for (int nb = 0; nb < 8; ++nb)
    *(us4*)(buf1 + (nb * 16 + lr) * LD1 + w * 16 + lg * 4) =
        pack4(sacc[nb][0], sacc[nb][1], sacc[nb][2], sacc[nb][3]);
  __syncthreads();   // b1: supT visible

  // ---------------- G4: dense = gate_d*(adj @ support) + support + b -> dnp ----------------
  unsigned int dnp[8][2];
  {
    const float* ajr = adjg + (size_t)b * (NN * NN) + arow * NN;
    bf8 aa[2];
    #pragma unroll
    for (int kb = 0; kb < 2; ++kb) {
      float4 p0 = *(const float4*)(ajr + kb * 32 + kcol);
      float4 p1 = *(const float4*)(ajr + kb * 32 + kcol + 4);
      aa[kb] = pk8(p0, p1);
    }
    #pragma unroll
    for (int nb = 0; nb < 8; ++nb) {
      f32x4 dacc = zz;
      #pragma unroll
      for (int kb = 0; kb < 2; ++kb) {
        bf8 bb = *(const bf8*)(buf1 + (nb * 16 + lr) * LD1 + kb * 32 + kcol);
        dacc = __builtin_amdgcn_mfma_f32_16x16x32_bf16(aa[kb], bb, dacc, 0, 0, 0);
      }
      float bc = bvec[nb * 16 + lr];
      float d0 = unpk(gdp[nb][0], 0) * dacc[0] + sacc[nb][0] + bc;
      float d1 = unpk(gdp[nb][0], 1) * dacc[1] + sacc[nb][1] + bc;
      float d2 = unpk(gdp[nb][1], 0) * dacc[2] + sacc[nb][2] + bc;
      float d3 = unpk(gdp[nb][1], 1) * dacc[3] + sacc[nb][3] + bc;
      dnp[nb][0] = pk2(d0, d1); dnp[nb][1] = pk2(d2, d3);
    }
  }
  // sacc, gdp dead here.

  // ---------------- G2: Whk = h @ Wk (K=96) ----------------
  f32x4 wacc[8] = {zz, zz, zz, zz, zz, zz, zz, zz};
  #pragma unroll
  for (int kb = 0; kb < 3; ++kb) {
    #pragma unroll
    for (int nb = 0; nb < 8; ++nb) {
      bf8 bb = *(const bf8*)(WkT + (nb * 3 + kb) * 512 + l * 8);     // coalesced frag
      wacc[nb] = __builtin_amdgcn_mfma_f32_16x16x32_bf16(ha[kb], bb, wacc[nb], 0, 0, 0);
    }
  }
  __syncthreads();   // b2: all supT reads (G4) done; buf1/buf2 free

  // Whk^T -> buf1 ; Whk row-major -> buf2 (wacc dies)
  #pragma unroll
  for (int nb = 0; nb < 8; ++nb) {
    int o = nb * 16 + lr;
    *(us4*)(buf1 + o * LD1 + w * 16 + lg * 4) =
        pack4(wacc[nb][0], wacc[nb][1], wacc[nb][2], wacc[nb][3]);
    #pragma unroll
    for (int r = 0; r < 4; ++r)
      buf2[(w * 16 + lg * 4 + r) * LD2 + o] = f2bf(wacc[nb][r]);
  }

  // ---------------- G3g: gate_g (oa dies after) ----------------
  unsigned int ggp[8][2];
  {
    f32x4 gg[8] = {zz, zz, zz, zz, zz, zz, zz, zz};
    #pragma unroll
    for (int kb = 0; kb < 2; ++kb) {
      #pragma unroll
      for (int nb = 0; nb < 8; ++nb) {
        bf8 bb = *(const bf8*)(WgT + (nb * 2 + kb) * 512 + l * 8);   // coalesced frag
        gg[nb] = __builtin_amdgcn_mfma_f32_16x16x32_bf16(oa[kb], bb, gg[nb], 0, 0, 0);
      }
    }
    #pragma unroll
    for (int nb = 0; nb < 8; ++nb) {
      float bo = bopg[nb * 16 + lr];
      float g0 = 1.f / (1.f + __expf(-(gg[nb][0] + bo)));
      float g1 = 1.f / (1.f + __expf(-(gg[nb][1] + bo)));
      float g2 = 1.f / (1.f + __expf(-(gg[nb][2] + bo)));
      float g3 = 1.f / (1.f + __expf(-(gg[nb][3] + bo)));
      ggp[nb][0] = pk2(g0, g1); ggp[nb][1] = pk2(g2, g3);
    }
  }
  __syncthreads();   // b3: whk + whkT visible

  // ---------------- G5: scores = (Whk * a_w) @ Whk^T (K=128) ----------------
  f32x4 sc[4] = {zz, zz, zz, zz};
  #pragma unroll
  for (int kb = 0; kb < 4; ++kb) {
    bf8 ar = *(const bf8*)(buf2 + arow * LD2 + kb * 32 + kcol);
    const float4* ap = (const float4*)(awv + kb * 32 + kcol);
    float4 a0 = ap[0], a1 = ap[1];
    bf8 a;
    a[0] = (short)f2bf(bf2f((unsigned short)ar[0]) * a0.x);
    a[1] = (short)f2bf(bf2f((unsigned short)ar[1]) * a0.y);
    a[2] = (short)f2bf(bf2f((unsigned short)ar[2]) * a0.z);
    a[3] = (short)f2bf(bf2f((unsigned short)ar[3]) * a0.w);
    a[4] = (short)f2bf(bf2f((unsigned short)ar[4]) * a1.x);
    a[5] = (short)f2bf(bf2f((unsigned short)ar[5]) * a1.y);
    a[6] = (short)f2bf(bf2f((unsigned short)ar[6]) * a1.z);
    a[7] = (short)f2bf(bf2f((unsigned short)ar[7]) * a1.w);
    #pragma unroll
    for (int jb = 0; jb < 4; ++jb) {
      bf8 bb = *(const bf8*)(buf2 + (jb * 16 + lr) * LD2 + kb * 32 + kcol);
      sc[jb] = __builtin_amdgcn_mfma_f32_16x16x32_bf16(a, bb, sc[jb], 0, 0, 0);
    }
  }

  // ---------------- softmax over j (leaky_relu then adj mask; mask loaded at use) ----------
  float al[4][4];
  #pragma unroll
  for (int jb = 0; jb < 4; ++jb)
    #pragma unroll
    for (int r = 0; r < 4; ++r) {
      float am = adjg[(size_t)b * (NN * NN) + (rowb + r) * NN + jb * 16 + lr];
      float s = sc[jb][r];
      al[jb][r] = (s >= 0.f ? s : 0.01f * s) * am;
    }
  #pragma unroll
  for (int r = 0; r < 4; ++r) {
    float m = fmaxf(fmaxf(al[0][r], al[1][r]), fmaxf(al[2][r], al[3][r]));
    m = fmaxf(m, __shfl_xor(m, 1));
    m = fmaxf(m, __shfl_xor(m, 2));
    m = fmaxf(m, __shfl_xor(m, 4));
    m = fmaxf(m, __shfl_xor(m, 8));
    float s0 = 0.f;
    #pragma unroll
    for (int jb = 0; jb < 4; ++jb) { float p = __expf(al[jb][r] - m); al[jb][r] = p; s0 += p; }
    s0 += __shfl_xor(s0, 1);
    s0 += __shfl_xor(s0, 2);
    s0 += __shfl_xor(s0, 4);
    s0 += __shfl_xor(s0, 8);
    float inv = 1.f / s0;
    #pragma unroll
    for (int jb = 0; jb < 4; ++jb) al[jb][r] *= inv;
  }
  __syncthreads();   // b4: all G5 reads of buf2 done -> attn may overwrite

  unsigned short* attn_s = buf2;   // [64][LDA] overlay
  #pragma unroll
  for (int jb = 0; jb < 4; ++jb)
    #pragma unroll
    for (int r = 0; r < 4; ++r)
      attn_s[(rowb + r) * LDA + jb * 16 + lr] = f2bf(al[jb][r]);  // own wave's rows only

  // ---------------- G6: hp = attn @ Whk (A: own attn rows; B: whkT in buf1) ----------------
  f32x4 hpacc[8] = {zz, zz, zz, zz, zz, zz, zz, zz};
  #pragma unroll
  for (int kb = 0; kb < 2; ++kb) {
    bf8 a = *(const bf8*)(attn_s + arow * LDA + kb * 32 + kcol);
    #pragma unroll
    for (int nb = 0; nb < 8; ++nb) {
      bf8 bb = *(const bf8*)(buf1 + (nb * 16 + lr) * LD1 + kb * 32 + kcol);
      hpacc[nb] = __builtin_amdgcn_mfma_f32_16x16x32_bf16(a, bb, hpacc[nb], 0, 0, 0);
    }
  }

  // ---------------- gate_g * hp, LayerNorm, combine with dnp, store ----------------
  float gam[8], bet[8];
  #pragma unroll
  for (int nb = 0; nb < 8; ++nb) { gam[nb] = gmv[nb * 16 + lr]; bet[nb] = btv[nb * 16 + lr]; }
  #pragma unroll
  for (int r = 0; r < 4; ++r) {
    float hv[8]; float su = 0.f, sq = 0.f;
    #pragma unroll
    for (int nb = 0; nb < 8; ++nb) {
      float v = unpk(ggp[nb][r >> 1], r & 1) * hpacc[nb][r];
      hv[nb] = v; su += v; sq += v * v;
    }
    su += __shfl_xor(su, 1); su += __shfl_xor(su, 2);
    su += __shfl_xor(su, 4); su += __shfl_xor(su, 8);
    sq += __shfl_xor(sq, 1); sq += __shfl_xor(sq, 2);
    sq += __shfl_xor(sq, 4); sq += __shfl_xor(sq, 8);
    float mean = su * (1.f / 128.f);
    float var  = sq * (1.f / 128.f) - mean * mean;
    float rinv = rsqrtf(var + 1e-5f);
    int row = rowb + r;
    #pragma unroll
    for (int nb = 0; nb < 8; ++nb) {
      float hn = (hv[nb] - mean) * rinv * gam[nb] + bet[nb];
      float dv = unpk(dnp[nb][r >> 1], r & 1);
      outp[row * 128 + nb * 16 + lr] = (dv + hn) * 0.5f;
    }
  }
}

extern "C" void kernel_launch(void* const* d_in, const int* in_sizes, int n_in,
                              void* d_out, int out_size, void* d_ws, size_t ws_size,
                              hipStream_t stream) {
  const float* h     = (const float*)d_in[0];
  const float* adj   = (const float*)d_in[1];
  const float* ope   = (const float*)d_in[2];
  const float* W     = (const float*)d_in[3];
  const float* bvec  = (const float*)d_in[4];
  const float* Wopd  = (const float*)d_in[5];
  const float* bopd  = (const float*)d_in[6];
  const float* Wk    = (const float*)d_in[7];
  const float* a_w   = (const float*)d_in[8];
  const float* Wopg  = (const float*)d_in[9];
  const float* bopg  = (const float*)d_in[10];
  const float* gamma = (const float*)d_in[11];
  const float* beta  = (const float*)d_in[12];
  float* out = (float*)d_out;
  unsigned short* ws = (unsigned short*)d_ws;

  prep_weights<<<dim3(160), dim3(256), 0, stream>>>(W, Wk, Wopd, Wopg, ws);
  gin_fused<<<dim3(NB), dim3(256), 0, stream>>>(h, adj, ope, bvec, bopd, bopg,
                                                a_w, gamma, beta, ws, out);
}